// Round 20
// baseline (460.327 us; speedup 1.0000x reference)
//
#include <hip/hip_runtime.h>
#include <hip/hip_fp16.h>

#define N_NODES 50000
#define NFEAT   256
#define NGRAPH  64
#define NEDGE   800000
#define NBUCK   98      // ceil(50000/512) buckets of 512 nodes
#define BWIN    16384   // fixed tmp window per bucket

typedef __attribute__((ext_vector_type(8))) _Float16 half8;
typedef __attribute__((ext_vector_type(2))) _Float16 h2v;
typedef __attribute__((ext_vector_type(4))) float f32x4;
struct alignas(8) US4 { unsigned short x, y, z, w; };

static __device__ __forceinline__ float h2f(unsigned short u) {
    return __half2float(__ushort_as_half(u));
}
static __device__ __forceinline__ unsigned short f2h(float f) {
    return __half_as_ushort(__float2half(f));
}

// ================= W prep (runs FIRST; also zeroes bcnt) =================
__global__ void k_prep_w(const float* __restrict__ W1, const float* __restrict__ W2,
                         unsigned short* __restrict__ w1t, unsigned short* __restrict__ w2t,
                         int* __restrict__ bcnt) {
    const int l = blockIdx.x >> 8;
    const int idx = (blockIdx.x & 255) * 256 + threadIdx.x;
    const int n = idx >> 8, k = idx & 255;
    const float* W = l ? W2 : W1;
    unsigned short* wt = l ? w2t : w1t;
    wt[n * 256 + k] = f2h(W[k * 256 + n]);
    if (l == 0 && blockIdx.x == 0 && threadIdx.x < NBUCK) bcnt[threadIdx.x] = 0;
}

// ================= CSR build, phase A: bin edges into buckets =================
__global__ __launch_bounds__(256) void k_bin(const int* __restrict__ src,
                                             const int* __restrict__ dst,
                                             int* __restrict__ bcnt,
                                             unsigned int* __restrict__ tmp) {
    __shared__ int hist[NBUCK];
    __shared__ int base[NBUCK];
    const int t = threadIdx.x;
    if (t < NBUCK) hist[t] = 0;
    __syncthreads();
    const int e0 = blockIdx.x * 1024 + t * 4;
    int s[4], d[4], b[4], rk[4];
#pragma unroll
    for (int i = 0; i < 4; ++i) {
        const int e = e0 + i;
        if (e < NEDGE) {
            s[i] = src[e];
            d[i] = dst[e];
            b[i] = d[i] >> 9;
            rk[i] = atomicAdd(&hist[b[i]], 1);
        } else {
            b[i] = -1;
        }
    }
    __syncthreads();
    if (t < NBUCK) base[t] = atomicAdd(&bcnt[t], hist[t]);
    __syncthreads();
#pragma unroll
    for (int i = 0; i < 4; ++i) {
        if (b[i] >= 0)
            tmp[(size_t)b[i] * BWIN + base[b[i]] + rk[i]] =
                ((unsigned int)s[i] << 16) | (unsigned int)d[i];
    }
}

// ================= phase B: per-bucket count/scan/place (+inline bucket prefix) ========
__global__ __launch_bounds__(256) void k_build(const unsigned int* __restrict__ tmp,
                                               const int* __restrict__ bcnt,
                                               int* __restrict__ row_start,
                                               float* __restrict__ dinv,
                                               unsigned short* __restrict__ csr) {
    __shared__ int cnt[512];
    __shared__ int cur[512];
    __shared__ int wtot[4];
    __shared__ int s_gb;
    const int bk = blockIdx.x, t = threadIdx.x;
    const int node0 = bk << 9;
    const int n = bcnt[bk];
    const unsigned int* rec = tmp + (size_t)bk * BWIN;
    cnt[t] = 0;
    cnt[t + 256] = 0;
    if (t < 64) {
        int part = 0;
        for (int i = t; i < bk; i += 64) part += bcnt[i];
#pragma unroll
        for (int off = 32; off; off >>= 1) part += __shfl_down(part, off, 64);
        if (t == 0) s_gb = part;
    }
    __syncthreads();
    for (int i = t; i < n; i += 256) atomicAdd(&cnt[rec[i] & 511], 1);
    __syncthreads();
    const int lane = t & 63, w = t >> 6;
    const int v0 = cnt[2 * t], v1 = cnt[2 * t + 1];
    const int ps = v0 + v1;
    int incl = ps;
#pragma unroll
    for (int off = 1; off < 64; off <<= 1) {
        int u = __shfl_up(incl, off, 64);
        if (lane >= off) incl += u;
    }
    if (lane == 63) wtot[w] = incl;
    __syncthreads();
    int wbase = 0;
#pragma unroll
    for (int k = 0; k < 4; ++k) wbase += (k < w) ? wtot[k] : 0;
    const int excl = wbase + incl - ps;
    const int gb = s_gb;
    const int g0 = node0 + 2 * t;
    if (g0 < N_NODES) {
        row_start[g0] = gb + excl;
        dinv[g0] = rsqrtf((float)v0 + 1.0f);
    }
    if (g0 + 1 < N_NODES) {
        row_start[g0 + 1] = gb + excl + v0;
        dinv[g0 + 1] = rsqrtf((float)v1 + 1.0f);
    }
    cur[2 * t] = gb + excl;
    cur[2 * t + 1] = gb + excl + v0;
    __syncthreads();
    for (int i = t; i < n; i += 256) {
        const unsigned int r = rec[i];
        const int pos = atomicAdd(&cur[r & 511], 1);
        csr[pos] = (unsigned short)(r >> 16);
    }
    if (bk == 0 && t == 0) row_start[N_NODES] = NEDGE;
}

// ================= fp16 MFMA GEMM: Chs[half][node][128] = dinv .* (A @ W) ==========
// A-READ-ONCE, 3 barriers, ks-pipelined ds_reads, swapped-operand epilogue.
template <bool AF32>
__global__ __launch_bounds__(256) void k_gemm_mfma(const float* __restrict__ Af,
                                                   const unsigned short* __restrict__ Ah,
                                                   const unsigned short* __restrict__ Wt,
                                                   const float* __restrict__ dinv,
                                                   unsigned short* __restrict__ Ch, int M) {
    __shared__ unsigned short lds[32768];
    const int t = threadIdx.x;
    const int m0 = blockIdx.x * 128;
    const int w = t >> 6, lane = t & 63;
    const int lr = lane & 15, g = lane >> 4;

    int boff[8];
#pragma unroll
    for (int ni = 0; ni < 8; ++ni) {
        const int n = ni * 16 + lr;
        boff[ni] = n * 32 + ((g ^ ((n >> 1) & 3)) << 3);
    }

    const int rbase = m0 + w * 32;
    half8 aA[8], aB[8];

#define STAGE(H)                                                                         \
    {                                                                                    \
        const unsigned short* wbase = Wt + (size_t)(H) * 128 * 256;                      \
        _Pragma("unroll") for (int it = 0; it < 16; ++it) {                              \
            const int unit = it * 256 + t;                                               \
            const int n = unit >> 5;                                                     \
            const int rem = unit & 31;                                                   \
            const int ks = rem >> 2, kg = rem & 3;                                       \
            const half8 v = *(const half8*)&wbase[n * 256 + rem * 8];                    \
            const int kgx = kg ^ ((n >> 1) & 3);                                         \
            *(half8*)&lds[ks * 4096 + n * 32 + kgx * 8] = v;                             \
        }                                                                                \
    }

#define LOADCHUNK(C, DST)                                                                \
    {                                                                                    \
        const int row = min(rbase + (C) * 16 + lr, M - 1);                               \
        _Pragma("unroll") for (int ks = 0; ks < 8; ++ks) {                               \
            if (AF32) {                                                                  \
                const float* ap = Af + (size_t)row * 256 + ks * 32 + g * 8;              \
                const float4 p0 = *(const float4*)ap;                                    \
                const float4 p1 = *(const float4*)(ap + 4);                              \
                half8 h;                                                                 \
                h[0] = (_Float16)p0.x; h[1] = (_Float16)p0.y;                            \
                h[2] = (_Float16)p0.z; h[3] = (_Float16)p0.w;                            \
                h[4] = (_Float16)p1.x; h[5] = (_Float16)p1.y;                            \
                h[6] = (_Float16)p1.z; h[7] = (_Float16)p1.w;                            \
                DST[ks] = h;                                                             \
            } else {                                                                     \
                DST[ks] = *(const half8*)(Ah + (size_t)(ks >> 2) * (size_t)N_NODES * 128 \
                                          + (size_t)row * 128 + (ks & 3) * 32 + g * 8);  \
            }                                                                            \
        }                                                                                \
    }

#define COMPUTE(C, SRC, H)                                                               \
    {                                                                                    \
        unsigned short* Chh = Ch + (size_t)(H) * (size_t)N_NODES * 128;                  \
        f32x4 acc[8] = {};                                                               \
        half8 bc[8];                                                                     \
        _Pragma("unroll") for (int ni = 0; ni < 8; ++ni)                                 \
            bc[ni] = *(const half8*)&lds[boff[ni]];                                      \
        _Pragma("unroll") for (int ks = 0; ks < 8; ++ks) {                               \
            half8 bn[8];                                                                 \
            if (ks < 7) {                                                                \
                _Pragma("unroll") for (int ni = 0; ni < 8; ++ni)                         \
                    bn[ni] = *(const half8*)&lds[(ks + 1) * 4096 + boff[ni]];            \
            }                                                                            \
            _Pragma("unroll") for (int ni = 0; ni < 8; ++ni)                             \
                acc[ni] = __builtin_amdgcn_mfma_f32_16x16x32_f16(bc[ni], SRC[ks],        \
                                                                 acc[ni], 0, 0, 0);      \
            _Pragma("unroll") for (int ni = 0; ni < 8; ++ni) bc[ni] = bn[ni];            \
        }                                                                                \
        const int row = rbase + (C) * 16 + lr;                                           \
        const float dv = dinv[min(row, M - 1)];                                          \
        if (row < M) {                                                                   \
            _Pragma("unroll") for (int ni = 0; ni < 8; ++ni) {                           \
                US4 o;                                                                   \
                o.x = f2h(acc[ni][0] * dv); o.y = f2h(acc[ni][1] * dv);                  \
                o.z = f2h(acc[ni][2] * dv); o.w = f2h(acc[ni][3] * dv);                  \
                *(US4*)(Chh + (size_t)row * 128 + ni * 16 + g * 4) = o;                  \
            }                                                                            \
        }                                                                                \
    }

    STAGE(0)
    __syncthreads();
    LOADCHUNK(0, aA)
    LOADCHUNK(1, aB)
    COMPUTE(0, aA, 0)
    COMPUTE(1, aB, 0)
    __syncthreads();
    STAGE(1)
    __syncthreads();
    COMPUTE(0, aA, 1)
    COMPUTE(1, aB, 1)

#undef STAGE
#undef LOADCHUNK
#undef COMPUTE
}

// ================= aggregation: out[d] = relu(b + dinv[d]*(hs[d] + sum hs[s])) =========
// wave per (node, half); 16 lanes/edge; edge loop unrolled x16 (8 pairs in flight).
__global__ __launch_bounds__(256) void k_aggregate(const unsigned short* __restrict__ hs,
                                                   const int* __restrict__ row_start,
                                                   const unsigned short* __restrict__ csr,
                                                   const float* __restrict__ dinv,
                                                   const float* __restrict__ bias,
                                                   unsigned short* __restrict__ out) {
    const int wid = blockIdx.x * 4 + (threadIdx.x >> 6);
    if (wid >= 2 * N_NODES) return;
    const int half = (wid >= N_NODES) ? 1 : 0;
    const int node = wid - half * N_NODES;
    const int lane = threadIdx.x & 63;
    const int sub = lane >> 4;
    const int fl = lane & 15;
    const unsigned int* hu = (const unsigned int*)(hs + (size_t)half * N_NODES * 128);
    const h2v e0v = {(_Float16)1.0f, (_Float16)0.0f};
    const h2v e1v = {(_Float16)0.0f, (_Float16)1.0f};

    float acc[8] = {};
    const int s0 = row_start[node], s1 = row_start[node + 1];
    const unsigned short* row = csr + s0;
    const int n = s1 - s0;

#define EDGEPAIR(VA, VB)                                                                   \
    {                                                                                      \
        h2v s;                                                                             \
        s = __builtin_bit_cast(h2v, VA.x) + __builtin_bit_cast(h2v, VB.x);                 \
        acc[0] = __builtin_amdgcn_fdot2(s, e0v, acc[0], false);                            \
        acc[1] = __builtin_amdgcn_fdot2(s, e1v, acc[1], false);                            \
        s = __builtin_bit_cast(h2v, VA.y) + __builtin_bit_cast(h2v, VB.y);                 \
        acc[2] = __builtin_amdgcn_fdot2(s, e0v, acc[2], false);                            \
        acc[3] = __builtin_amdgcn_fdot2(s, e1v, acc[3], false);                            \
        s = __builtin_bit_cast(h2v, VA.z) + __builtin_bit_cast(h2v, VB.z);                 \
        acc[4] = __builtin_amdgcn_fdot2(s, e0v, acc[4], false);                            \
        acc[5] = __builtin_amdgcn_fdot2(s, e1v, acc[5], false);                            \
        s = __builtin_bit_cast(h2v, VA.w) + __builtin_bit_cast(h2v, VB.w);                 \
        acc[6] = __builtin_amdgcn_fdot2(s, e0v, acc[6], false);                            \
        acc[7] = __builtin_amdgcn_fdot2(s, e1v, acc[7], false);                            \
    }

    const int nfull = n & ~15;
    int j = 0;
    for (; j < nfull; j += 16) {  // 16 edges (4 pairs/sub-slot x 4 slots... 2 pairs/slot)
        const int a0 = row[j + sub * 2];
        const int b0 = row[j + sub * 2 + 1];
        const int a1 = row[j + 8 + sub * 2];
        const int b1 = row[j + 8 + sub * 2 + 1];
        const uint4 va0 = *(const uint4*)(hu + (size_t)a0 * 64 + fl * 4);
        const uint4 vb0 = *(const uint4*)(hu + (size_t)b0 * 64 + fl * 4);
        const uint4 va1 = *(const uint4*)(hu + (size_t)a1 * 64 + fl * 4);
        const uint4 vb1 = *(const uint4*)(hu + (size_t)b1 * 64 + fl * 4);
        EDGEPAIR(va0, vb0)
        EDGEPAIR(va1, vb1)
    }
    for (; j < n; j += 8) {  // guarded tail (up to 15 edges -> at most 2 iterations)
        const int ia = j + sub * 2, ib = ia + 1;
        uint4 va = {0, 0, 0, 0}, vb = {0, 0, 0, 0};
        if (ia < n) va = *(const uint4*)(hu + (size_t)row[ia] * 64 + fl * 4);
        if (ib < n) vb = *(const uint4*)(hu + (size_t)row[ib] * 64 + fl * 4);
        EDGEPAIR(va, vb)
    }
#undef EDGEPAIR

#pragma unroll
    for (int i = 0; i < 8; ++i) {
        acc[i] += __shfl_xor(acc[i], 16, 64);
        acc[i] += __shfl_xor(acc[i], 32, 64);
    }

    if (sub == 0) {
        const float dd = dinv[node];
        const uint4 sh = *(const uint4*)(hu + (size_t)node * 64 + fl * 4);
        const float4 b0 = *(const float4*)(bias + half * 128 + fl * 8);
        const float4 b1 = *(const float4*)(bias + half * 128 + fl * 8 + 4);
        float r[8];
        r[0] = fmaf(acc[0] + h2f((unsigned short)(sh.x & 0xffff)), dd, b0.x);
        r[1] = fmaf(acc[1] + h2f((unsigned short)(sh.x >> 16)),    dd, b0.y);
        r[2] = fmaf(acc[2] + h2f((unsigned short)(sh.y & 0xffff)), dd, b0.z);
        r[3] = fmaf(acc[3] + h2f((unsigned short)(sh.y >> 16)),    dd, b0.w);
        r[4] = fmaf(acc[4] + h2f((unsigned short)(sh.z & 0xffff)), dd, b1.x);
        r[5] = fmaf(acc[5] + h2f((unsigned short)(sh.z >> 16)),    dd, b1.y);
        r[6] = fmaf(acc[6] + h2f((unsigned short)(sh.w & 0xffff)), dd, b1.z);
        r[7] = fmaf(acc[7] + h2f((unsigned short)(sh.w >> 16)),    dd, b1.w);
#pragma unroll
        for (int i = 0; i < 8; ++i) r[i] = fmaxf(r[i], 0.f);
        uint4 o;
        o.x = (unsigned int)f2h(r[0]) | ((unsigned int)f2h(r[1]) << 16);
        o.y = (unsigned int)f2h(r[2]) | ((unsigned int)f2h(r[3]) << 16);
        o.z = (unsigned int)f2h(r[4]) | ((unsigned int)f2h(r[5]) << 16);
        o.w = (unsigned int)f2h(r[6]) | ((unsigned int)f2h(r[7]) << 16);
        *(uint4*)((unsigned int*)(out + (size_t)half * N_NODES * 128) +
                  (size_t)node * 64 + fl * 4) = o;
    }
}

// ================= fused pooling + head: one block per graph, no atomics ============
// batch sorted -> binary search graph boundaries; thread t owns feature
// (half = t>>7, c = t&127); out[g] = sum_n relu'd hB dot Wout + bout.
__global__ __launch_bounds__(256) void k_pool_final(const unsigned short* __restrict__ hB,
                                                    const int* __restrict__ batch,
                                                    const float* __restrict__ Wout,
                                                    const float* __restrict__ bout,
                                                    float* __restrict__ out) {
    const int g = blockIdx.x, t = threadIdx.x;
    int lo = 0, hi = N_NODES;
    while (lo < hi) { const int mid = (lo + hi) >> 1; if (batch[mid] < g) lo = mid + 1; else hi = mid; }
    int lo2 = lo, hi2 = N_NODES;
    while (lo2 < hi2) { const int mid = (lo2 + hi2) >> 1; if (batch[mid] < g + 1) lo2 = mid + 1; else hi2 = mid; }

    const int half = t >> 7, c = t & 127;
    const unsigned short* base = hB + (size_t)half * N_NODES * 128 + c;
    float sum = 0.f;
    for (int n = lo; n < lo2; ++n) sum += h2f(base[(size_t)n * 128]);
    float v = sum * Wout[half * 128 + c];
#pragma unroll
    for (int off = 32; off; off >>= 1) v += __shfl_down(v, off, 64);
    __shared__ float sred[4];
    if ((t & 63) == 0) sred[t >> 6] = v;
    __syncthreads();
    if (t == 0) out[g] = sred[0] + sred[1] + sred[2] + sred[3] + bout[0];
}

extern "C" void kernel_launch(void* const* d_in, const int* in_sizes, int n_in,
                              void* d_out, int out_size, void* d_ws, size_t ws_size,
                              hipStream_t stream) {
    const float* x     = (const float*)d_in[0];
    const int*   ei    = (const int*)d_in[1];
    const int*   batch = (const int*)d_in[2];
    const float* W1    = (const float*)d_in[3];
    const float* b1    = (const float*)d_in[4];
    const float* W2    = (const float*)d_in[5];
    const float* b2    = (const float*)d_in[6];
    const float* Wout  = (const float*)d_in[7];
    const float* bout  = (const float*)d_in[8];
    float* out = (float*)d_out;

    const int* srcp = ei;
    const int* dstp = ei + NEDGE;

    const size_t NE128 = (size_t)N_NODES * 128;
    unsigned short* hA = (unsigned short*)d_ws;            // [2][N][128] fp16 (dinv-scaled)
    unsigned short* hB = hA + 2 * NE128;                   // [2][N][128] fp16
    float* dinv      = (float*)(hB + 2 * NE128);           // 50000
    int*   row_start = (int*)(dinv + N_NODES);             // 50001 (+pad)
    int*   bcnt      = row_start + N_NODES + 3;            // 98
    unsigned short* csr = (unsigned short*)(bcnt + NBUCK + 2);  // 800000 ushort
    unsigned int* tmp = (unsigned int*)(csr + NEDGE);      // 98*16384 uint
    unsigned short* w1t = (unsigned short*)(tmp + (size_t)NBUCK * BWIN);  // 65536 each
    unsigned short* w2t = w1t + 65536;

    // ---- prep (also zeroes bcnt) ----
    k_prep_w<<<512, 256, 0, stream>>>(W1, W2, w1t, w2t, bcnt);

    // ---- CSR build ----
    k_bin<<<(NEDGE + 1023) / 1024, 256, 0, stream>>>(srcp, dstp, bcnt, tmp);
    k_build<<<NBUCK, 256, 0, stream>>>(tmp, bcnt, row_start, dinv, csr);

    const int ggrid = 391;
    const int agg_grid = (2 * N_NODES + 3) / 4;  // 25000

    // ---- layer 1 ----
    k_gemm_mfma<true><<<ggrid, 256, 0, stream>>>(x, nullptr, w1t, dinv, hA, N_NODES);
    k_aggregate<<<agg_grid, 256, 0, stream>>>(hA, row_start, csr, dinv, b1, hB);

    // ---- layer 2 ----
    k_gemm_mfma<false><<<ggrid, 256, 0, stream>>>(nullptr, hB, w2t, dinv, hA, N_NODES);
    k_aggregate<<<agg_grid, 256, 0, stream>>>(hA, row_start, csr, dinv, b2, hB);

    // ---- fused pooling + head ----
    k_pool_final<<<NGRAPH, 256, 0, stream>>>(hB, batch, Wout, bout, out);
}

// Round 21
// 252.173 us; speedup vs baseline: 1.8254x; 1.8254x over previous
//
#include <hip/hip_runtime.h>
#include <hip/hip_fp16.h>

#define N_NODES 50000
#define NFEAT   256
#define NGRAPH  64
#define NEDGE   800000
#define NBUCK   98      // ceil(50000/512) buckets of 512 nodes
#define BWIN    16384   // fixed tmp window per bucket

typedef __attribute__((ext_vector_type(8))) _Float16 half8;
typedef __attribute__((ext_vector_type(2))) _Float16 h2v;
typedef __attribute__((ext_vector_type(4))) float f32x4;
struct alignas(8) US4 { unsigned short x, y, z, w; };

static __device__ __forceinline__ float h2f(unsigned short u) {
    return __half2float(__ushort_as_half(u));
}
static __device__ __forceinline__ unsigned short f2h(float f) {
    return __half_as_ushort(__float2half(f));
}

// ================= W prep (runs FIRST; also zeroes bcnt + pooled) =================
__global__ void k_prep_w(const float* __restrict__ W1, const float* __restrict__ W2,
                         unsigned short* __restrict__ w1t, unsigned short* __restrict__ w2t,
                         int* __restrict__ bcnt, float* __restrict__ pooled) {
    const int l = blockIdx.x >> 8;
    const int idx = (blockIdx.x & 255) * 256 + threadIdx.x;
    const int n = idx >> 8, k = idx & 255;
    const float* W = l ? W2 : W1;
    unsigned short* wt = l ? w2t : w1t;
    wt[n * 256 + k] = f2h(W[k * 256 + n]);
    if (l == 0) {
        if (blockIdx.x == 0 && threadIdx.x < NBUCK) bcnt[threadIdx.x] = 0;
        if (blockIdx.x >= 1 && blockIdx.x <= 64) {
            const int p = (blockIdx.x - 1) * 256 + threadIdx.x;
            if (p < NGRAPH * NFEAT) pooled[p] = 0.f;
        }
    }
}

// ================= CSR build, phase A: bin edges into buckets =================
__global__ __launch_bounds__(256) void k_bin(const int* __restrict__ src,
                                             const int* __restrict__ dst,
                                             int* __restrict__ bcnt,
                                             unsigned int* __restrict__ tmp) {
    __shared__ int hist[NBUCK];
    __shared__ int base[NBUCK];
    const int t = threadIdx.x;
    if (t < NBUCK) hist[t] = 0;
    __syncthreads();
    const int e0 = blockIdx.x * 1024 + t * 4;
    int s[4], d[4], b[4], rk[4];
#pragma unroll
    for (int i = 0; i < 4; ++i) {
        const int e = e0 + i;
        if (e < NEDGE) {
            s[i] = src[e];
            d[i] = dst[e];
            b[i] = d[i] >> 9;
            rk[i] = atomicAdd(&hist[b[i]], 1);
        } else {
            b[i] = -1;
        }
    }
    __syncthreads();
    if (t < NBUCK) base[t] = atomicAdd(&bcnt[t], hist[t]);
    __syncthreads();
#pragma unroll
    for (int i = 0; i < 4; ++i) {
        if (b[i] >= 0)
            tmp[(size_t)b[i] * BWIN + base[b[i]] + rk[i]] =
                ((unsigned int)s[i] << 16) | (unsigned int)d[i];
    }
}

// ================= phase B: per-bucket count/scan/place (+inline bucket prefix) ========
__global__ __launch_bounds__(256) void k_build(const unsigned int* __restrict__ tmp,
                                               const int* __restrict__ bcnt,
                                               int* __restrict__ row_start,
                                               float* __restrict__ dinv,
                                               unsigned short* __restrict__ csr) {
    __shared__ int cnt[512];
    __shared__ int cur[512];
    __shared__ int wtot[4];
    __shared__ int s_gb;
    const int bk = blockIdx.x, t = threadIdx.x;
    const int node0 = bk << 9;
    const int n = bcnt[bk];
    const unsigned int* rec = tmp + (size_t)bk * BWIN;
    cnt[t] = 0;
    cnt[t + 256] = 0;
    if (t < 64) {
        int part = 0;
        for (int i = t; i < bk; i += 64) part += bcnt[i];
#pragma unroll
        for (int off = 32; off; off >>= 1) part += __shfl_down(part, off, 64);
        if (t == 0) s_gb = part;
    }
    __syncthreads();
    for (int i = t; i < n; i += 256) atomicAdd(&cnt[rec[i] & 511], 1);
    __syncthreads();
    const int lane = t & 63, w = t >> 6;
    const int v0 = cnt[2 * t], v1 = cnt[2 * t + 1];
    const int ps = v0 + v1;
    int incl = ps;
#pragma unroll
    for (int off = 1; off < 64; off <<= 1) {
        int u = __shfl_up(incl, off, 64);
        if (lane >= off) incl += u;
    }
    if (lane == 63) wtot[w] = incl;
    __syncthreads();
    int wbase = 0;
#pragma unroll
    for (int k = 0; k < 4; ++k) wbase += (k < w) ? wtot[k] : 0;
    const int excl = wbase + incl - ps;
    const int gb = s_gb;
    const int g0 = node0 + 2 * t;
    if (g0 < N_NODES) {
        row_start[g0] = gb + excl;
        dinv[g0] = rsqrtf((float)v0 + 1.0f);
    }
    if (g0 + 1 < N_NODES) {
        row_start[g0 + 1] = gb + excl + v0;
        dinv[g0 + 1] = rsqrtf((float)v1 + 1.0f);
    }
    cur[2 * t] = gb + excl;
    cur[2 * t + 1] = gb + excl + v0;
    __syncthreads();
    for (int i = t; i < n; i += 256) {
        const unsigned int r = rec[i];
        const int pos = atomicAdd(&cur[r & 511], 1);
        csr[pos] = (unsigned short)(r >> 16);
    }
    if (bk == 0 && t == 0) row_start[N_NODES] = NEDGE;
}

// ================= fp16 MFMA GEMM: Chs[half][node][128] = dinv .* (A @ W) ==========
// A-READ-ONCE, 3 barriers, ks-pipelined ds_reads, swapped-operand epilogue.
template <bool AF32>
__global__ __launch_bounds__(256) void k_gemm_mfma(const float* __restrict__ Af,
                                                   const unsigned short* __restrict__ Ah,
                                                   const unsigned short* __restrict__ Wt,
                                                   const float* __restrict__ dinv,
                                                   unsigned short* __restrict__ Ch, int M) {
    __shared__ unsigned short lds[32768];
    const int t = threadIdx.x;
    const int m0 = blockIdx.x * 128;
    const int w = t >> 6, lane = t & 63;
    const int lr = lane & 15, g = lane >> 4;

    int boff[8];
#pragma unroll
    for (int ni = 0; ni < 8; ++ni) {
        const int n = ni * 16 + lr;
        boff[ni] = n * 32 + ((g ^ ((n >> 1) & 3)) << 3);
    }

    const int rbase = m0 + w * 32;
    half8 aA[8], aB[8];

#define STAGE(H)                                                                         \
    {                                                                                    \
        const unsigned short* wbase = Wt + (size_t)(H) * 128 * 256;                      \
        _Pragma("unroll") for (int it = 0; it < 16; ++it) {                              \
            const int unit = it * 256 + t;                                               \
            const int n = unit >> 5;                                                     \
            const int rem = unit & 31;                                                   \
            const int ks = rem >> 2, kg = rem & 3;                                       \
            const half8 v = *(const half8*)&wbase[n * 256 + rem * 8];                    \
            const int kgx = kg ^ ((n >> 1) & 3);                                         \
            *(half8*)&lds[ks * 4096 + n * 32 + kgx * 8] = v;                             \
        }                                                                                \
    }

#define LOADCHUNK(C, DST)                                                                \
    {                                                                                    \
        const int row = min(rbase + (C) * 16 + lr, M - 1);                               \
        _Pragma("unroll") for (int ks = 0; ks < 8; ++ks) {                               \
            if (AF32) {                                                                  \
                const float* ap = Af + (size_t)row * 256 + ks * 32 + g * 8;              \
                const float4 p0 = *(const float4*)ap;                                    \
                const float4 p1 = *(const float4*)(ap + 4);                              \
                half8 h;                                                                 \
                h[0] = (_Float16)p0.x; h[1] = (_Float16)p0.y;                            \
                h[2] = (_Float16)p0.z; h[3] = (_Float16)p0.w;                            \
                h[4] = (_Float16)p1.x; h[5] = (_Float16)p1.y;                            \
                h[6] = (_Float16)p1.z; h[7] = (_Float16)p1.w;                            \
                DST[ks] = h;                                                             \
            } else {                                                                     \
                DST[ks] = *(const half8*)(Ah + (size_t)(ks >> 2) * (size_t)N_NODES * 128 \
                                          + (size_t)row * 128 + (ks & 3) * 32 + g * 8);  \
            }                                                                            \
        }                                                                                \
    }

#define COMPUTE(C, SRC, H)                                                               \
    {                                                                                    \
        unsigned short* Chh = Ch + (size_t)(H) * (size_t)N_NODES * 128;                  \
        f32x4 acc[8] = {};                                                               \
        half8 bc[8];                                                                     \
        _Pragma("unroll") for (int ni = 0; ni < 8; ++ni)                                 \
            bc[ni] = *(const half8*)&lds[boff[ni]];                                      \
        _Pragma("unroll") for (int ks = 0; ks < 8; ++ks) {                               \
            half8 bn[8];                                                                 \
            if (ks < 7) {                                                                \
                _Pragma("unroll") for (int ni = 0; ni < 8; ++ni)                         \
                    bn[ni] = *(const half8*)&lds[(ks + 1) * 4096 + boff[ni]];            \
            }                                                                            \
            _Pragma("unroll") for (int ni = 0; ni < 8; ++ni)                             \
                acc[ni] = __builtin_amdgcn_mfma_f32_16x16x32_f16(bc[ni], SRC[ks],        \
                                                                 acc[ni], 0, 0, 0);      \
            _Pragma("unroll") for (int ni = 0; ni < 8; ++ni) bc[ni] = bn[ni];            \
        }                                                                                \
        const int row = rbase + (C) * 16 + lr;                                           \
        const float dv = dinv[min(row, M - 1)];                                          \
        if (row < M) {                                                                   \
            _Pragma("unroll") for (int ni = 0; ni < 8; ++ni) {                           \
                US4 o;                                                                   \
                o.x = f2h(acc[ni][0] * dv); o.y = f2h(acc[ni][1] * dv);                  \
                o.z = f2h(acc[ni][2] * dv); o.w = f2h(acc[ni][3] * dv);                  \
                *(US4*)(Chh + (size_t)row * 128 + ni * 16 + g * 4) = o;                  \
            }                                                                            \
        }                                                                                \
    }

    STAGE(0)
    __syncthreads();
    LOADCHUNK(0, aA)
    LOADCHUNK(1, aB)
    COMPUTE(0, aA, 0)
    COMPUTE(1, aB, 0)
    __syncthreads();
    STAGE(1)
    __syncthreads();
    COMPUTE(0, aA, 1)
    COMPUTE(1, aB, 1)

#undef STAGE
#undef LOADCHUNK
#undef COMPUTE
}

// ================= aggregation: out[d] = relu(b + dinv[d]*(hs[d] + sum hs[s])) =========
// wave per (node, half); 16 lanes/edge; edge loop unrolled x16 (8 pairs in flight).
__global__ __launch_bounds__(256) void k_aggregate(const unsigned short* __restrict__ hs,
                                                   const int* __restrict__ row_start,
                                                   const unsigned short* __restrict__ csr,
                                                   const float* __restrict__ dinv,
                                                   const float* __restrict__ bias,
                                                   unsigned short* __restrict__ out) {
    const int wid = blockIdx.x * 4 + (threadIdx.x >> 6);
    if (wid >= 2 * N_NODES) return;
    const int half = (wid >= N_NODES) ? 1 : 0;
    const int node = wid - half * N_NODES;
    const int lane = threadIdx.x & 63;
    const int sub = lane >> 4;
    const int fl = lane & 15;
    const unsigned int* hu = (const unsigned int*)(hs + (size_t)half * N_NODES * 128);
    const h2v e0v = {(_Float16)1.0f, (_Float16)0.0f};
    const h2v e1v = {(_Float16)0.0f, (_Float16)1.0f};

    float acc[8] = {};
    const int s0 = row_start[node], s1 = row_start[node + 1];
    const unsigned short* row = csr + s0;
    const int n = s1 - s0;

#define EDGEPAIR(VA, VB)                                                                   \
    {                                                                                      \
        h2v s;                                                                             \
        s = __builtin_bit_cast(h2v, VA.x) + __builtin_bit_cast(h2v, VB.x);                 \
        acc[0] = __builtin_amdgcn_fdot2(s, e0v, acc[0], false);                            \
        acc[1] = __builtin_amdgcn_fdot2(s, e1v, acc[1], false);                            \
        s = __builtin_bit_cast(h2v, VA.y) + __builtin_bit_cast(h2v, VB.y);                 \
        acc[2] = __builtin_amdgcn_fdot2(s, e0v, acc[2], false);                            \
        acc[3] = __builtin_amdgcn_fdot2(s, e1v, acc[3], false);                            \
        s = __builtin_bit_cast(h2v, VA.z) + __builtin_bit_cast(h2v, VB.z);                 \
        acc[4] = __builtin_amdgcn_fdot2(s, e0v, acc[4], false);                            \
        acc[5] = __builtin_amdgcn_fdot2(s, e1v, acc[5], false);                            \
        s = __builtin_bit_cast(h2v, VA.w) + __builtin_bit_cast(h2v, VB.w);                 \
        acc[6] = __builtin_amdgcn_fdot2(s, e0v, acc[6], false);                            \
        acc[7] = __builtin_amdgcn_fdot2(s, e1v, acc[7], false);                            \
    }

    const int nfull = n & ~15;
    int j = 0;
    for (; j < nfull; j += 16) {
        const int a0 = row[j + sub * 2];
        const int b0 = row[j + sub * 2 + 1];
        const int a1 = row[j + 8 + sub * 2];
        const int b1 = row[j + 8 + sub * 2 + 1];
        const uint4 va0 = *(const uint4*)(hu + (size_t)a0 * 64 + fl * 4);
        const uint4 vb0 = *(const uint4*)(hu + (size_t)b0 * 64 + fl * 4);
        const uint4 va1 = *(const uint4*)(hu + (size_t)a1 * 64 + fl * 4);
        const uint4 vb1 = *(const uint4*)(hu + (size_t)b1 * 64 + fl * 4);
        EDGEPAIR(va0, vb0)
        EDGEPAIR(va1, vb1)
    }
    for (; j < n; j += 8) {
        const int ia = j + sub * 2, ib = ia + 1;
        uint4 va = {0, 0, 0, 0}, vb = {0, 0, 0, 0};
        if (ia < n) va = *(const uint4*)(hu + (size_t)row[ia] * 64 + fl * 4);
        if (ib < n) vb = *(const uint4*)(hu + (size_t)row[ib] * 64 + fl * 4);
        EDGEPAIR(va, vb)
    }
#undef EDGEPAIR

#pragma unroll
    for (int i = 0; i < 8; ++i) {
        acc[i] += __shfl_xor(acc[i], 16, 64);
        acc[i] += __shfl_xor(acc[i], 32, 64);
    }

    if (sub == 0) {
        const float dd = dinv[node];
        const uint4 sh = *(const uint4*)(hu + (size_t)node * 64 + fl * 4);
        const float4 b0 = *(const float4*)(bias + half * 128 + fl * 8);
        const float4 b1 = *(const float4*)(bias + half * 128 + fl * 8 + 4);
        float r[8];
        r[0] = fmaf(acc[0] + h2f((unsigned short)(sh.x & 0xffff)), dd, b0.x);
        r[1] = fmaf(acc[1] + h2f((unsigned short)(sh.x >> 16)),    dd, b0.y);
        r[2] = fmaf(acc[2] + h2f((unsigned short)(sh.y & 0xffff)), dd, b0.z);
        r[3] = fmaf(acc[3] + h2f((unsigned short)(sh.y >> 16)),    dd, b0.w);
        r[4] = fmaf(acc[4] + h2f((unsigned short)(sh.z & 0xffff)), dd, b1.x);
        r[5] = fmaf(acc[5] + h2f((unsigned short)(sh.z >> 16)),    dd, b1.y);
        r[6] = fmaf(acc[6] + h2f((unsigned short)(sh.w & 0xffff)), dd, b1.z);
        r[7] = fmaf(acc[7] + h2f((unsigned short)(sh.w >> 16)),    dd, b1.w);
#pragma unroll
        for (int i = 0; i < 8; ++i) r[i] = fmaxf(r[i], 0.f);
        uint4 o;
        o.x = (unsigned int)f2h(r[0]) | ((unsigned int)f2h(r[1]) << 16);
        o.y = (unsigned int)f2h(r[2]) | ((unsigned int)f2h(r[3]) << 16);
        o.z = (unsigned int)f2h(r[4]) | ((unsigned int)f2h(r[5]) << 16);
        o.w = (unsigned int)f2h(r[6]) | ((unsigned int)f2h(r[7]) << 16);
        *(uint4*)((unsigned int*)(out + (size_t)half * N_NODES * 128) +
                  (size_t)node * 64 + fl * 4) = o;
    }
}

// ================= pooling (batch sorted, 625 blocks, strip-atomic) =================
__global__ void k_pool(const unsigned short* __restrict__ h2, const int* __restrict__ batch,
                       float* __restrict__ pooled) {
    const int strip = blockIdx.x * 2 + (threadIdx.x >> 7);
    const int tf = threadIdx.x & 127;
    const int f = tf * 2;
    const unsigned short* base = h2 + (size_t)(f >> 7) * N_NODES * 128 + (f & 127);
    const int n0 = strip * 40, n1 = n0 + 40;
    int g = batch[n0];
    float ax = 0.f, ay = 0.f;
    for (int n = n0; n < n1; ++n) {
        const int bg = batch[n];
        if (bg != g) {
            unsafeAtomicAdd(&pooled[g * NFEAT + f], ax);
            unsafeAtomicAdd(&pooled[g * NFEAT + f + 1], ay);
            ax = ay = 0.f;
            g = bg;
        }
        const unsigned int u = *(const unsigned int*)(base + (size_t)n * 128);
        ax += h2f((unsigned short)(u & 0xffff));
        ay += h2f((unsigned short)(u >> 16));
    }
    unsafeAtomicAdd(&pooled[g * NFEAT + f], ax);
    unsafeAtomicAdd(&pooled[g * NFEAT + f + 1], ay);
}

__global__ void k_final(const float* __restrict__ pooled, const float* __restrict__ Wout,
                        const float* __restrict__ bout, float* __restrict__ out) {
    const int g = blockIdx.x, t = threadIdx.x;
    float v = pooled[g * NFEAT + t] * Wout[t];
#pragma unroll
    for (int off = 32; off > 0; off >>= 1) v += __shfl_down(v, off, 64);
    __shared__ float sred[4];
    if ((t & 63) == 0) sred[t >> 6] = v;
    __syncthreads();
    if (t == 0) out[g] = sred[0] + sred[1] + sred[2] + sred[3] + bout[0];
}

extern "C" void kernel_launch(void* const* d_in, const int* in_sizes, int n_in,
                              void* d_out, int out_size, void* d_ws, size_t ws_size,
                              hipStream_t stream) {
    const float* x     = (const float*)d_in[0];
    const int*   ei    = (const int*)d_in[1];
    const int*   batch = (const int*)d_in[2];
    const float* W1    = (const float*)d_in[3];
    const float* b1    = (const float*)d_in[4];
    const float* W2    = (const float*)d_in[5];
    const float* b2    = (const float*)d_in[6];
    const float* Wout  = (const float*)d_in[7];
    const float* bout  = (const float*)d_in[8];
    float* out = (float*)d_out;

    const int* srcp = ei;
    const int* dstp = ei + NEDGE;

    const size_t NE128 = (size_t)N_NODES * 128;
    unsigned short* hA = (unsigned short*)d_ws;            // [2][N][128] fp16 (dinv-scaled)
    unsigned short* hB = hA + 2 * NE128;                   // [2][N][128] fp16
    float* dinv      = (float*)(hB + 2 * NE128);           // 50000
    float* pooled    = dinv + N_NODES;                     // 16384
    int*   row_start = (int*)(pooled + NGRAPH * NFEAT);    // 50001 (+pad)
    int*   bcnt      = row_start + N_NODES + 3;            // 98
    unsigned short* csr = (unsigned short*)(bcnt + NBUCK + 2);  // 800000 ushort
    unsigned int* tmp = (unsigned int*)(csr + NEDGE);      // 98*16384 uint
    unsigned short* w1t = (unsigned short*)(tmp + (size_t)NBUCK * BWIN);  // 65536 each
    unsigned short* w2t = w1t + 65536;

    // ---- prep (also zeroes bcnt + pooled) ----
    k_prep_w<<<512, 256, 0, stream>>>(W1, W2, w1t, w2t, bcnt, pooled);

    // ---- CSR build ----
    k_bin<<<(NEDGE + 1023) / 1024, 256, 0, stream>>>(srcp, dstp, bcnt, tmp);
    k_build<<<NBUCK, 256, 0, stream>>>(tmp, bcnt, row_start, dinv, csr);

    const int ggrid = 391;
    const int agg_grid = (2 * N_NODES + 3) / 4;  // 25000

    // ---- layer 1 ----
    k_gemm_mfma<true><<<ggrid, 256, 0, stream>>>(x, nullptr, w1t, dinv, hA, N_NODES);
    k_aggregate<<<agg_grid, 256, 0, stream>>>(hA, row_start, csr, dinv, b1, hB);

    // ---- layer 2 ----
    k_gemm_mfma<false><<<ggrid, 256, 0, stream>>>(nullptr, hB, w2t, dinv, hA, N_NODES);
    k_aggregate<<<agg_grid, 256, 0, stream>>>(hA, row_start, csr, dinv, b2, hB);

    // ---- pooling + head ----
    k_pool<<<625, 256, 0, stream>>>(hB, batch, pooled);
    k_final<<<NGRAPH, 256, 0, stream>>>(pooled, Wout, bout, out);
}

// Round 22
// 249.364 us; speedup vs baseline: 1.8460x; 1.0113x over previous
//
#include <hip/hip_runtime.h>
#include <hip/hip_fp16.h>

#define N_NODES 50000
#define NFEAT   256
#define NGRAPH  64
#define NEDGE   800000
#define NBUCK   98      // ceil(50000/512) buckets of 512 nodes
#define BWIN    16384   // fixed tmp window per bucket

typedef __attribute__((ext_vector_type(8))) _Float16 half8;
typedef __attribute__((ext_vector_type(2))) _Float16 h2v;
typedef __attribute__((ext_vector_type(4))) float f32x4;
struct alignas(8) US4 { unsigned short x, y, z, w; };

static __device__ __forceinline__ float h2f(unsigned short u) {
    return __half2float(__ushort_as_half(u));
}
static __device__ __forceinline__ unsigned short f2h(float f) {
    return __half_as_ushort(__float2half(f));
}

// ================= W prep (runs FIRST; also zeroes bcnt + pooled) =================
__global__ void k_prep_w(const float* __restrict__ W1, const float* __restrict__ W2,
                         unsigned short* __restrict__ w1t, unsigned short* __restrict__ w2t,
                         int* __restrict__ bcnt, float* __restrict__ pooled) {
    const int l = blockIdx.x >> 8;
    const int idx = (blockIdx.x & 255) * 256 + threadIdx.x;
    const int n = idx >> 8, k = idx & 255;
    const float* W = l ? W2 : W1;
    unsigned short* wt = l ? w2t : w1t;
    wt[n * 256 + k] = f2h(W[k * 256 + n]);
    if (l == 0) {
        if (blockIdx.x == 0 && threadIdx.x < NBUCK) bcnt[threadIdx.x] = 0;
        if (blockIdx.x >= 1 && blockIdx.x <= 64) {
            const int p = (blockIdx.x - 1) * 256 + threadIdx.x;
            if (p < NGRAPH * NFEAT) pooled[p] = 0.f;
        }
    }
}

// ================= CSR build, phase A: bin edges into buckets =================
__global__ __launch_bounds__(256) void k_bin(const int* __restrict__ src,
                                             const int* __restrict__ dst,
                                             int* __restrict__ bcnt,
                                             unsigned int* __restrict__ tmp) {
    __shared__ int hist[NBUCK];
    __shared__ int base[NBUCK];
    const int t = threadIdx.x;
    if (t < NBUCK) hist[t] = 0;
    __syncthreads();
    const int e0 = blockIdx.x * 1024 + t * 4;
    int s[4], d[4], b[4], rk[4];
#pragma unroll
    for (int i = 0; i < 4; ++i) {
        const int e = e0 + i;
        if (e < NEDGE) {
            s[i] = src[e];
            d[i] = dst[e];
            b[i] = d[i] >> 9;
            rk[i] = atomicAdd(&hist[b[i]], 1);
        } else {
            b[i] = -1;
        }
    }
    __syncthreads();
    if (t < NBUCK) base[t] = atomicAdd(&bcnt[t], hist[t]);
    __syncthreads();
#pragma unroll
    for (int i = 0; i < 4; ++i) {
        if (b[i] >= 0)
            tmp[(size_t)b[i] * BWIN + base[b[i]] + rk[i]] =
                ((unsigned int)s[i] << 16) | (unsigned int)d[i];
    }
}

// ================= phase B: per-bucket count/scan/place (+inline bucket prefix) ========
__global__ __launch_bounds__(256) void k_build(const unsigned int* __restrict__ tmp,
                                               const int* __restrict__ bcnt,
                                               int* __restrict__ row_start,
                                               float* __restrict__ dinv,
                                               unsigned short* __restrict__ csr) {
    __shared__ int cnt[512];
    __shared__ int cur[512];
    __shared__ int wtot[4];
    __shared__ int s_gb;
    const int bk = blockIdx.x, t = threadIdx.x;
    const int node0 = bk << 9;
    const int n = bcnt[bk];
    const unsigned int* rec = tmp + (size_t)bk * BWIN;
    cnt[t] = 0;
    cnt[t + 256] = 0;
    if (t < 64) {
        int part = 0;
        for (int i = t; i < bk; i += 64) part += bcnt[i];
#pragma unroll
        for (int off = 32; off; off >>= 1) part += __shfl_down(part, off, 64);
        if (t == 0) s_gb = part;
    }
    __syncthreads();
    for (int i = t; i < n; i += 256) atomicAdd(&cnt[rec[i] & 511], 1);
    __syncthreads();
    const int lane = t & 63, w = t >> 6;
    const int v0 = cnt[2 * t], v1 = cnt[2 * t + 1];
    const int ps = v0 + v1;
    int incl = ps;
#pragma unroll
    for (int off = 1; off < 64; off <<= 1) {
        int u = __shfl_up(incl, off, 64);
        if (lane >= off) incl += u;
    }
    if (lane == 63) wtot[w] = incl;
    __syncthreads();
    int wbase = 0;
#pragma unroll
    for (int k = 0; k < 4; ++k) wbase += (k < w) ? wtot[k] : 0;
    const int excl = wbase + incl - ps;
    const int gb = s_gb;
    const int g0 = node0 + 2 * t;
    if (g0 < N_NODES) {
        row_start[g0] = gb + excl;
        dinv[g0] = rsqrtf((float)v0 + 1.0f);
    }
    if (g0 + 1 < N_NODES) {
        row_start[g0 + 1] = gb + excl + v0;
        dinv[g0 + 1] = rsqrtf((float)v1 + 1.0f);
    }
    cur[2 * t] = gb + excl;
    cur[2 * t + 1] = gb + excl + v0;
    __syncthreads();
    for (int i = t; i < n; i += 256) {
        const unsigned int r = rec[i];
        const int pos = atomicAdd(&cur[r & 511], 1);
        csr[pos] = (unsigned short)(r >> 16);
    }
    if (bk == 0 && t == 0) row_start[N_NODES] = NEDGE;
}

// ================= fp16 MFMA GEMM: Chs[half][node][128] = dinv .* (A @ W) ==========
// A-READ-ONCE + A-loads issued BEFORE the first barrier (HBM latency hidden under
// W staging + barrier drain). launch_bounds(256,2) restores VGPR headroom for the
// ks-pipelined ds_reads. Swapped-operand epilogue (packed 8B stores).
template <bool AF32>
__global__ __launch_bounds__(256, 2) void k_gemm_mfma(const float* __restrict__ Af,
                                                      const unsigned short* __restrict__ Ah,
                                                      const unsigned short* __restrict__ Wt,
                                                      const float* __restrict__ dinv,
                                                      unsigned short* __restrict__ Ch, int M) {
    __shared__ unsigned short lds[32768];
    const int t = threadIdx.x;
    const int m0 = blockIdx.x * 128;
    const int w = t >> 6, lane = t & 63;
    const int lr = lane & 15, g = lane >> 4;

    int boff[8];
#pragma unroll
    for (int ni = 0; ni < 8; ++ni) {
        const int n = ni * 16 + lr;
        boff[ni] = n * 32 + ((g ^ ((n >> 1) & 3)) << 3);
    }

    const int rbase = m0 + w * 32;
    half8 aA[8], aB[8];

#define LOADCHUNK(C, DST)                                                                \
    {                                                                                    \
        const int row = min(rbase + (C) * 16 + lr, M - 1);                               \
        _Pragma("unroll") for (int ks = 0; ks < 8; ++ks) {                               \
            if (AF32) {                                                                  \
                const float* ap = Af + (size_t)row * 256 + ks * 32 + g * 8;              \
                const float4 p0 = *(const float4*)ap;                                    \
                const float4 p1 = *(const float4*)(ap + 4);                              \
                half8 h;                                                                 \
                h[0] = (_Float16)p0.x; h[1] = (_Float16)p0.y;                            \
                h[2] = (_Float16)p0.z; h[3] = (_Float16)p0.w;                            \
                h[4] = (_Float16)p1.x; h[5] = (_Float16)p1.y;                            \
                h[6] = (_Float16)p1.z; h[7] = (_Float16)p1.w;                            \
                DST[ks] = h;                                                             \
            } else {                                                                     \
                DST[ks] = *(const half8*)(Ah + (size_t)(ks >> 2) * (size_t)N_NODES * 128 \
                                          + (size_t)row * 128 + (ks & 3) * 32 + g * 8);  \
            }                                                                            \
        }                                                                                \
    }

#define STAGE(H)                                                                         \
    {                                                                                    \
        const unsigned short* wbase = Wt + (size_t)(H) * 128 * 256;                      \
        _Pragma("unroll") for (int it = 0; it < 16; ++it) {                              \
            const int unit = it * 256 + t;                                               \
            const int n = unit >> 5;                                                     \
            const int rem = unit & 31;                                                   \
            const int ks = rem >> 2, kg = rem & 3;                                       \
            const half8 v = *(const half8*)&wbase[n * 256 + rem * 8];                    \
            const int kgx = kg ^ ((n >> 1) & 3);                                         \
            *(half8*)&lds[ks * 4096 + n * 32 + kgx * 8] = v;                             \
        }                                                                                \
    }

#define COMPUTE(C, SRC, H)                                                               \
    {                                                                                    \
        unsigned short* Chh = Ch + (size_t)(H) * (size_t)N_NODES * 128;                  \
        f32x4 acc[8] = {};                                                               \
        half8 bc[8];                                                                     \
        _Pragma("unroll") for (int ni = 0; ni < 8; ++ni)                                 \
            bc[ni] = *(const half8*)&lds[boff[ni]];                                      \
        _Pragma("unroll") for (int ks = 0; ks < 8; ++ks) {                               \
            half8 bn[8];                                                                 \
            if (ks < 7) {                                                                \
                _Pragma("unroll") for (int ni = 0; ni < 8; ++ni)                         \
                    bn[ni] = *(const half8*)&lds[(ks + 1) * 4096 + boff[ni]];            \
            }                                                                            \
            _Pragma("unroll") for (int ni = 0; ni < 8; ++ni)                             \
                acc[ni] = __builtin_amdgcn_mfma_f32_16x16x32_f16(bc[ni], SRC[ks],        \
                                                                 acc[ni], 0, 0, 0);      \
            _Pragma("unroll") for (int ni = 0; ni < 8; ++ni) bc[ni] = bn[ni];            \
        }                                                                                \
        const int row = rbase + (C) * 16 + lr;                                           \
        const float dv = dinv[min(row, M - 1)];                                          \
        if (row < M) {                                                                   \
            _Pragma("unroll") for (int ni = 0; ni < 8; ++ni) {                           \
                US4 o;                                                                   \
                o.x = f2h(acc[ni][0] * dv); o.y = f2h(acc[ni][1] * dv);                  \
                o.z = f2h(acc[ni][2] * dv); o.w = f2h(acc[ni][3] * dv);                  \
                *(US4*)(Chh + (size_t)row * 128 + ni * 16 + g * 4) = o;                  \
            }                                                                            \
        }                                                                                \
    }

    LOADCHUNK(0, aA)   // A-loads issued FIRST: HBM latency overlaps staging+barrier
    LOADCHUNK(1, aB)
    STAGE(0)
    __syncthreads();
    COMPUTE(0, aA, 0)
    COMPUTE(1, aB, 0)
    __syncthreads();
    STAGE(1)
    __syncthreads();
    COMPUTE(0, aA, 1)
    COMPUTE(1, aB, 1)

#undef STAGE
#undef LOADCHUNK
#undef COMPUTE
}

// ================= aggregation: out[d] = relu(b + dinv[d]*(hs[d] + sum hs[s])) =========
// wave per (node, half); 16 lanes/edge; edge loop unrolled x16.
__global__ __launch_bounds__(256) void k_aggregate(const unsigned short* __restrict__ hs,
                                                   const int* __restrict__ row_start,
                                                   const unsigned short* __restrict__ csr,
                                                   const float* __restrict__ dinv,
                                                   const float* __restrict__ bias,
                                                   unsigned short* __restrict__ out) {
    const int wid = blockIdx.x * 4 + (threadIdx.x >> 6);
    if (wid >= 2 * N_NODES) return;
    const int half = (wid >= N_NODES) ? 1 : 0;
    const int node = wid - half * N_NODES;
    const int lane = threadIdx.x & 63;
    const int sub = lane >> 4;
    const int fl = lane & 15;
    const unsigned int* hu = (const unsigned int*)(hs + (size_t)half * N_NODES * 128);
    const h2v e0v = {(_Float16)1.0f, (_Float16)0.0f};
    const h2v e1v = {(_Float16)0.0f, (_Float16)1.0f};

    float acc[8] = {};
    const int s0 = row_start[node], s1 = row_start[node + 1];
    const unsigned short* row = csr + s0;
    const int n = s1 - s0;

#define EDGEPAIR(VA, VB)                                                                   \
    {                                                                                      \
        h2v s;                                                                             \
        s = __builtin_bit_cast(h2v, VA.x) + __builtin_bit_cast(h2v, VB.x);                 \
        acc[0] = __builtin_amdgcn_fdot2(s, e0v, acc[0], false);                            \
        acc[1] = __builtin_amdgcn_fdot2(s, e1v, acc[1], false);                            \
        s = __builtin_bit_cast(h2v, VA.y) + __builtin_bit_cast(h2v, VB.y);                 \
        acc[2] = __builtin_amdgcn_fdot2(s, e0v, acc[2], false);                            \
        acc[3] = __builtin_amdgcn_fdot2(s, e1v, acc[3], false);                            \
        s = __builtin_bit_cast(h2v, VA.z) + __builtin_bit_cast(h2v, VB.z);                 \
        acc[4] = __builtin_amdgcn_fdot2(s, e0v, acc[4], false);                            \
        acc[5] = __builtin_amdgcn_fdot2(s, e1v, acc[5], false);                            \
        s = __builtin_bit_cast(h2v, VA.w) + __builtin_bit_cast(h2v, VB.w);                 \
        acc[6] = __builtin_amdgcn_fdot2(s, e0v, acc[6], false);                            \
        acc[7] = __builtin_amdgcn_fdot2(s, e1v, acc[7], false);                            \
    }

    const int nfull = n & ~15;
    int j = 0;
    for (; j < nfull; j += 16) {
        const int a0 = row[j + sub * 2];
        const int b0 = row[j + sub * 2 + 1];
        const int a1 = row[j + 8 + sub * 2];
        const int b1 = row[j + 8 + sub * 2 + 1];
        const uint4 va0 = *(const uint4*)(hu + (size_t)a0 * 64 + fl * 4);
        const uint4 vb0 = *(const uint4*)(hu + (size_t)b0 * 64 + fl * 4);
        const uint4 va1 = *(const uint4*)(hu + (size_t)a1 * 64 + fl * 4);
        const uint4 vb1 = *(const uint4*)(hu + (size_t)b1 * 64 + fl * 4);
        EDGEPAIR(va0, vb0)
        EDGEPAIR(va1, vb1)
    }
    for (; j < n; j += 8) {
        const int ia = j + sub * 2, ib = ia + 1;
        uint4 va = {0, 0, 0, 0}, vb = {0, 0, 0, 0};
        if (ia < n) va = *(const uint4*)(hu + (size_t)row[ia] * 64 + fl * 4);
        if (ib < n) vb = *(const uint4*)(hu + (size_t)row[ib] * 64 + fl * 4);
        EDGEPAIR(va, vb)
    }
#undef EDGEPAIR

#pragma unroll
    for (int i = 0; i < 8; ++i) {
        acc[i] += __shfl_xor(acc[i], 16, 64);
        acc[i] += __shfl_xor(acc[i], 32, 64);
    }

    if (sub == 0) {
        const float dd = dinv[node];
        const uint4 sh = *(const uint4*)(hu + (size_t)node * 64 + fl * 4);
        const float4 b0 = *(const float4*)(bias + half * 128 + fl * 8);
        const float4 b1 = *(const float4*)(bias + half * 128 + fl * 8 + 4);
        float r[8];
        r[0] = fmaf(acc[0] + h2f((unsigned short)(sh.x & 0xffff)), dd, b0.x);
        r[1] = fmaf(acc[1] + h2f((unsigned short)(sh.x >> 16)),    dd, b0.y);
        r[2] = fmaf(acc[2] + h2f((unsigned short)(sh.y & 0xffff)), dd, b0.z);
        r[3] = fmaf(acc[3] + h2f((unsigned short)(sh.y >> 16)),    dd, b0.w);
        r[4] = fmaf(acc[4] + h2f((unsigned short)(sh.z & 0xffff)), dd, b1.x);
        r[5] = fmaf(acc[5] + h2f((unsigned short)(sh.z >> 16)),    dd, b1.y);
        r[6] = fmaf(acc[6] + h2f((unsigned short)(sh.w & 0xffff)), dd, b1.z);
        r[7] = fmaf(acc[7] + h2f((unsigned short)(sh.w >> 16)),    dd, b1.w);
#pragma unroll
        for (int i = 0; i < 8; ++i) r[i] = fmaxf(r[i], 0.f);
        uint4 o;
        o.x = (unsigned int)f2h(r[0]) | ((unsigned int)f2h(r[1]) << 16);
        o.y = (unsigned int)f2h(r[2]) | ((unsigned int)f2h(r[3]) << 16);
        o.z = (unsigned int)f2h(r[4]) | ((unsigned int)f2h(r[5]) << 16);
        o.w = (unsigned int)f2h(r[6]) | ((unsigned int)f2h(r[7]) << 16);
        *(uint4*)((unsigned int*)(out + (size_t)half * N_NODES * 128) +
                  (size_t)node * 64 + fl * 4) = o;
    }
}

// ================= pooling (batch sorted, 625 blocks, strip-atomic) =================
__global__ void k_pool(const unsigned short* __restrict__ h2, const int* __restrict__ batch,
                       float* __restrict__ pooled) {
    const int strip = blockIdx.x * 2 + (threadIdx.x >> 7);
    const int tf = threadIdx.x & 127;
    const int f = tf * 2;
    const unsigned short* base = h2 + (size_t)(f >> 7) * N_NODES * 128 + (f & 127);
    const int n0 = strip * 40, n1 = n0 + 40;
    int g = batch[n0];
    float ax = 0.f, ay = 0.f;
    for (int n = n0; n < n1; ++n) {
        const int bg = batch[n];
        if (bg != g) {
            unsafeAtomicAdd(&pooled[g * NFEAT + f], ax);
            unsafeAtomicAdd(&pooled[g * NFEAT + f + 1], ay);
            ax = ay = 0.f;
            g = bg;
        }
        const unsigned int u = *(const unsigned int*)(base + (size_t)n * 128);
        ax += h2f((unsigned short)(u & 0xffff));
        ay += h2f((unsigned short)(u >> 16));
    }
    unsafeAtomicAdd(&pooled[g * NFEAT + f], ax);
    unsafeAtomicAdd(&pooled[g * NFEAT + f + 1], ay);
}

__global__ void k_final(const float* __restrict__ pooled, const float* __restrict__ Wout,
                        const float* __restrict__ bout, float* __restrict__ out) {
    const int g = blockIdx.x, t = threadIdx.x;
    float v = pooled[g * NFEAT + t] * Wout[t];
#pragma unroll
    for (int off = 32; off > 0; off >>= 1) v += __shfl_down(v, off, 64);
    __shared__ float sred[4];
    if ((t & 63) == 0) sred[t >> 6] = v;
    __syncthreads();
    if (t == 0) out[g] = sred[0] + sred[1] + sred[2] + sred[3] + bout[0];
}

extern "C" void kernel_launch(void* const* d_in, const int* in_sizes, int n_in,
                              void* d_out, int out_size, void* d_ws, size_t ws_size,
                              hipStream_t stream) {
    const float* x     = (const float*)d_in[0];
    const int*   ei    = (const int*)d_in[1];
    const int*   batch = (const int*)d_in[2];
    const float* W1    = (const float*)d_in[3];
    const float* b1    = (const float*)d_in[4];
    const float* W2    = (const float*)d_in[5];
    const float* b2    = (const float*)d_in[6];
    const float* Wout  = (const float*)d_in[7];
    const float* bout  = (const float*)d_in[8];
    float* out = (float*)d_out;

    const int* srcp = ei;
    const int* dstp = ei + NEDGE;

    const size_t NE128 = (size_t)N_NODES * 128;
    unsigned short* hA = (unsigned short*)d_ws;            // [2][N][128] fp16 (dinv-scaled)
    unsigned short* hB = hA + 2 * NE128;                   // [2][N][128] fp16
    float* dinv      = (float*)(hB + 2 * NE128);           // 50000
    float* pooled    = dinv + N_NODES;                     // 16384
    int*   row_start = (int*)(pooled + NGRAPH * NFEAT);    // 50001 (+pad)
    int*   bcnt      = row_start + N_NODES + 3;            // 98
    unsigned short* csr = (unsigned short*)(bcnt + NBUCK + 2);  // 800000 ushort
    unsigned int* tmp = (unsigned int*)(csr + NEDGE);      // 98*16384 uint
    unsigned short* w1t = (unsigned short*)(tmp + (size_t)NBUCK * BWIN);  // 65536 each
    unsigned short* w2t = w1t + 65536;

    // ---- prep (also zeroes bcnt + pooled) ----
    k_prep_w<<<512, 256, 0, stream>>>(W1, W2, w1t, w2t, bcnt, pooled);

    // ---- CSR build ----
    k_bin<<<(NEDGE + 1023) / 1024, 256, 0, stream>>>(srcp, dstp, bcnt, tmp);
    k_build<<<NBUCK, 256, 0, stream>>>(tmp, bcnt, row_start, dinv, csr);

    const int ggrid = 391;
    const int agg_grid = (2 * N_NODES + 3) / 4;  // 25000

    // ---- layer 1 ----
    k_gemm_mfma<true><<<ggrid, 256, 0, stream>>>(x, nullptr, w1t, dinv, hA, N_NODES);
    k_aggregate<<<agg_grid, 256, 0, stream>>>(hA, row_start, csr, dinv, b1, hB);

    // ---- layer 2 ----
    k_gemm_mfma<false><<<ggrid, 256, 0, stream>>>(nullptr, hB, w2t, dinv, hA, N_NODES);
    k_aggregate<<<agg_grid, 256, 0, stream>>>(hA, row_start, csr, dinv, b2, hB);

    // ---- pooling + head ----
    k_pool<<<625, 256, 0, stream>>>(hB, batch, pooled);
    k_final<<<NGRAPH, 256, 0, stream>>>(pooled, Wout, bout, out);
}